// Round 11
// baseline (73.685 us; speedup 1.0000x reference)
//
#include <hip/hip_runtime.h>
#include <math.h>

// PartialAttention: LN -> Q/K proj -> scaled QK^T -> rowmax-subtracted exp.
// S=4096, B=2, E=1024, D=64. Out [B,S,S] f32 = 134 MB.
//
// Base = round-10 kernel (PASSED, 72.5 us). Scheduling-only changes in
// ln_proj: (1) batch 8 W-loads + 8 ds_reads per half-chunk into static
// register arrays before the MFMA chain; (2) dual accumulators accA/accB
// to halve the MFMA dependence chain; (3) __launch_bounds__(512,4) to cap
// VGPR <=128 (2 blocks/CU resident). Data path byte-identical to r10.
//
// Kernel W (wprep): W -> bf16 RNE hi/lo B-frag arrays (verbatim r5, proven).
// Kernel 1 (ln_proj): fused, 8 waves, 16 rows/block, dbuf LDS A-frags,
//   4-term hi/lo MFMA, proven epilogue + splitter, T14 async-STAGE split.
// Kernel S (score): verbatim r2/r5 (write-roofline).

typedef __attribute__((ext_vector_type(4))) float f32x4;
typedef __attribute__((ext_vector_type(8))) short bf16x8;
typedef __attribute__((ext_vector_type(8))) unsigned short u16x8;

#define SLEN 4096
#define BATCH 2
#define EDIM 1024
#define DDIM 64
#define QK_STRIDE 136    // q cols [0,64), k cols [68,132)

__device__ __forceinline__ unsigned short f2bf(float f) {
    unsigned int u = __float_as_uint(f);
    u += 0x7FFFu + ((u >> 16) & 1u);   // RNE to bf16
    return (unsigned short)(u >> 16);
}
__device__ __forceinline__ float bf2f(unsigned short h) {
    return __uint_as_float(((unsigned int)h) << 16);
}

// ---------------- kernel W: W fragment prep (verbatim r5, proven) ----------------
// slot = (ct*32 + kg)*64 + l; value j = W[kg*32 + ((l>>4)&3)*8 + j][ct*16 + (l&15)]
__global__ __launch_bounds__(256) void wprep_kernel(
    const float* __restrict__ Wq, const float* __restrict__ Wk,
    unsigned short* __restrict__ whf, unsigned short* __restrict__ wlf)
{
    const int slot = blockIdx.x * 256 + threadIdx.x;   // 0..16383
    const int ct = slot >> 11;
    const int kg = (slot >> 6) & 31;
    const int l  = slot & 63;
    const int c  = ct * 16 + (l & 15);
    const int kb = kg * 32 + ((l >> 4) & 3) * 8;
    const float* Wm = (c < DDIM) ? (Wq + c) : (Wk + (c - DDIM));
    u16x8 hv, lv;
#pragma unroll
    for (int j = 0; j < 8; ++j) {
        const float v = Wm[(size_t)(kb + j) * DDIM];
        const unsigned short h = f2bf(v);
        hv[j] = h;
        lv[j] = f2bf(v - bf2f(h));
    }
    *reinterpret_cast<u16x8*>(whf + (size_t)slot * 8) = hv;
    *reinterpret_cast<u16x8*>(wlf + (size_t)slot * 8) = lv;
}

// ---------------- kernel 1: LN + MFMA projection (r10 + batched loads) ----------------
__global__ __launch_bounds__(512, 4) void ln_proj_kernel(
    const float* __restrict__ src, const float* __restrict__ gamma,
    const float* __restrict__ beta,
    const float* __restrict__ bq, const float* __restrict__ bk,
    const unsigned short* __restrict__ whf, const unsigned short* __restrict__ wlf,
    unsigned short* __restrict__ qhf, unsigned short* __restrict__ qlf,
    unsigned short* __restrict__ khf, unsigned short* __restrict__ klf)
{
    __shared__ u16x8 xhf[2][8][64];        // 16 KB: A-frag hi, dbuf per chunk
    __shared__ u16x8 xlf[2][8][64];        // 16 KB: A-frag lo
    __shared__ float2 stats[16];
    __shared__ float qk[16 * QK_STRIDE];   // 8.7 KB
    const int tid  = threadIdx.x;
    const int lane = tid & 63;
    const int wv   = tid >> 6;             // 0..7
    const int gt   = blockIdx.x;           // 0..511
    const int b    = gt >> 8;
    const int s0   = (gt & 255) * 16;

    // ---- phase A: LN stats, 2 rows per wave (verbatim r10) ----
    for (int ii = 0; ii < 2; ++ii) {
        const int i = wv * 2 + ii;
        const float* row = src + ((size_t)(s0 + i) * BATCH + b) * EDIM;
        float sum = 0.f, sq = 0.f;
#pragma unroll
        for (int k = 0; k < 4; ++k) {
            float4 v = *reinterpret_cast<const float4*>(row + k * 256 + lane * 4);
            sum += v.x + v.y + v.z + v.w;
            sq  += v.x*v.x + v.y*v.y + v.z*v.z + v.w*v.w;
        }
#pragma unroll
        for (int off = 1; off < 64; off <<= 1) {
            sum += __shfl_xor(sum, off);
            sq  += __shfl_xor(sq,  off);
        }
        if (lane == 0) {
            const float mu   = sum * (1.f / EDIM);
            const float rstd = rsqrtf(sq * (1.f / EDIM) - mu * mu + 1e-5f);
            stats[i] = make_float2(mu, rstd);
        }
    }
    __syncthreads();

    // staging role (verbatim r10 mapping): frag slot (kg = wv, lane); reads 8
    // floats of row (lane&15) at col c*256 + wv*32 + (lane>>4)*8.
    const int srow = lane & 15;
    const int scol = wv * 32 + (lane >> 4) * 8;
    const float* srcrow = src + ((size_t)(s0 + srow) * BATCH + b) * EDIM;
    const float smu = stats[srow].x;
    const float srs = stats[srow].y;

    float4 Lva, Lvb, Lga, Lgb, Lba, Lbb;   // pipelined chunk registers

#define STAGE_LOAD(c)                                                         \
    {                                                                         \
        const int cb_ = (c) * 256 + scol;                                     \
        Lva = *reinterpret_cast<const float4*>(srcrow + cb_);                 \
        Lvb = *reinterpret_cast<const float4*>(srcrow + cb_ + 4);             \
        Lga = *reinterpret_cast<const float4*>(gamma + cb_);                  \
        Lgb = *reinterpret_cast<const float4*>(gamma + cb_ + 4);              \
        Lba = *reinterpret_cast<const float4*>(beta + cb_);                   \
        Lbb = *reinterpret_cast<const float4*>(beta + cb_ + 4);               \
    }

#define STAGE_FIN(bf)                                                         \
    {                                                                         \
        const float vv[8] = {                                                 \
            (Lva.x - smu) * srs * Lga.x + Lba.x,                              \
            (Lva.y - smu) * srs * Lga.y + Lba.y,                              \
            (Lva.z - smu) * srs * Lga.z + Lba.z,                              \
            (Lva.w - smu) * srs * Lga.w + Lba.w,                              \
            (Lvb.x - smu) * srs * Lgb.x + Lbb.x,                              \
            (Lvb.y - smu) * srs * Lgb.y + Lbb.y,                              \
            (Lvb.z - smu) * srs * Lgb.z + Lbb.z,                              \
            (Lvb.w - smu) * srs * Lgb.w + Lbb.w };                            \
        u16x8 hv, lv;                                                         \
        _Pragma("unroll")                                                     \
        for (int j = 0; j < 8; ++j) {                                         \
            const unsigned short h = f2bf(vv[j]);                             \
            hv[j] = h;                                                        \
            lv[j] = f2bf(vv[j] - bf2f(h));                                    \
        }                                                                     \
        xhf[bf][wv][lane] = hv;                                               \
        xlf[bf][wv][lane] = lv;                                               \
    }

    // compute role: wave wv owns col-tile ct = wv (verbatim r10)
    f32x4 accA = {0.f, 0.f, 0.f, 0.f};
    f32x4 accB = {0.f, 0.f, 0.f, 0.f};

    STAGE_LOAD(0);
    STAGE_FIN(0);
    __syncthreads();

    for (int c = 0; c < 4; ++c) {
        const int cur = c & 1;
        if (c < 3) STAGE_LOAD(c + 1);      // issue loads; hide under MFMAs
#pragma unroll
        for (int h = 0; h < 2; ++h) {      // half-chunk = 4 kg, batched
            bf16x8 Bh[4], Bl[4], Ah[4], Al[4];
#pragma unroll
            for (int k = 0; k < 4; ++k) {  // batch-issue 8 global + 8 LDS
                const int kg = h * 4 + k;
                const size_t wslot = ((size_t)wv * 32 + c * 8 + kg) * 64 + lane;
                Bh[k] = *reinterpret_cast<const bf16x8*>(whf + wslot * 8);
                Bl[k] = *reinterpret_cast<const bf16x8*>(wlf + wslot * 8);
                Ah[k] = *reinterpret_cast<const bf16x8*>(&xhf[cur][kg][lane]);
                Al[k] = *reinterpret_cast<const bf16x8*>(&xlf[cur][kg][lane]);
            }
#pragma unroll
            for (int k = 0; k < 4; ++k) {  // two independent MFMA chains
                accA = __builtin_amdgcn_mfma_f32_16x16x32_bf16(Ah[k], Bh[k], accA, 0, 0, 0);
                accB = __builtin_amdgcn_mfma_f32_16x16x32_bf16(Al[k], Bh[k], accB, 0, 0, 0);
                accA = __builtin_amdgcn_mfma_f32_16x16x32_bf16(Ah[k], Bl[k], accA, 0, 0, 0);
                accB = __builtin_amdgcn_mfma_f32_16x16x32_bf16(Al[k], Bl[k], accB, 0, 0, 0);
            }
        }
        if (c < 3) STAGE_FIN(cur ^ 1);     // wait+convert+write after MFMAs
        __syncthreads();
    }
#undef STAGE_LOAD
#undef STAGE_FIN

    // ---- epilogue (r10 + accA/accB merge): bias, f32 qk tile ----
    {
        const int cj = wv * 16 + (lane & 15);
        const int r0 = (lane >> 4) * 4;
        const float bv = (cj < DDIM) ? bq[cj] : bk[cj - DDIM];
        const int cb = (cj < DDIM) ? cj : (68 + cj - DDIM);
#pragma unroll
        for (int r = 0; r < 4; ++r)
            qk[(r0 + r) * QK_STRIDE + cb] = (accA[r] + accB[r]) + bv;
    }
    __syncthreads();

    // ---- phase 3 (verbatim r2/r5/r7, proven): RNE hi/lo split to frag order ----
    if (tid < 256) {
        const int l2  = tid & 63;
        const int dc  = (tid >> 6) & 1;
        const int isK = tid >> 7;
        const int row = l2 & 15;
        const int d0  = dc * 32 + ((l2 >> 4) & 3) * 8;
        const float* p = &qk[row * QK_STRIDE + (isK ? 68 : 0) + d0];
        const float sc = isK ? 1.0f : 0.125f;   // fold 1/sqrt(D) into q
        u16x8 hvv, lvv;
#pragma unroll
        for (int j = 0; j < 8; ++j) {
            const float vq = p[j] * sc;
            const unsigned short h = f2bf(vq);
            hvv[j] = h;
            lvv[j] = f2bf(vq - bf2f(h));
        }
        const size_t base = ((((size_t)b * 256 + (size_t)(gt & 255)) * 2 + dc) * 512) + (size_t)l2 * 8;
        *reinterpret_cast<u16x8*>((isK ? khf : qhf) + base) = hvv;
        *reinterpret_cast<u16x8*>((isK ? klf : qlf) + base) = lvv;
    }
}

// ---------------- kernel S: QK^T + rowmax + exp (verbatim r2/r5) ----------------
__global__ __launch_bounds__(1024, 1) void score_kernel(
    const unsigned short* __restrict__ qhf, const unsigned short* __restrict__ qlf,
    const unsigned short* __restrict__ khf, const unsigned short* __restrict__ klf,
    float* __restrict__ out)
{
    __shared__ float wmax[16 * 16];
    __shared__ float fmax_s[16];
    const int tid = threadIdx.x;
    const int l   = tid & 63;
    const int w   = tid >> 6;
    const int bid = blockIdx.x;
    const int b   = bid >> 8;
    const int rt  = bid & 255;

    const size_t abase = (((size_t)b * 256 + rt) * 2) * 512 + (size_t)l * 8;
    const bf16x8 qh0 = *reinterpret_cast<const bf16x8*>(qhf + abase);
    const bf16x8 qh1 = *reinterpret_cast<const bf16x8*>(qhf + abase + 512);
    const bf16x8 ql0 = *reinterpret_cast<const bf16x8*>(qlf + abase);
    const bf16x8 ql1 = *reinterpret_cast<const bf16x8*>(qlf + abase + 512);

    f32x4 acc[16];
#pragma unroll
    for (int i = 0; i < 16; ++i) acc[i] = (f32x4){0.f, 0.f, 0.f, 0.f};

#pragma unroll
    for (int i = 0; i < 16; ++i) {
        const int ct = w * 16 + i;
        const size_t kb = (((size_t)b * 256 + ct) * 2) * 512 + (size_t)l * 8;
        const bf16x8 kh0 = *reinterpret_cast<const bf16x8*>(khf + kb);
        const bf16x8 kh1 = *reinterpret_cast<const bf16x8*>(khf + kb + 512);
        const bf16x8 kl0 = *reinterpret_cast<const bf16x8*>(klf + kb);
        const bf16x8 kl1 = *reinterpret_cast<const bf16x8*>(klf + kb + 512);
        f32x4 a = acc[i];
        a = __builtin_amdgcn_mfma_f32_16x16x32_bf16(qh0, kh0, a, 0, 0, 0);
        a = __builtin_amdgcn_mfma_f32_16x16x32_bf16(qh1, kh1, a, 0, 0, 0);
        a = __builtin_amdgcn_mfma_f32_16x16x32_bf16(qh0, kl0, a, 0, 0, 0);
        a = __builtin_amdgcn_mfma_f32_16x16x32_bf16(qh1, kl1, a, 0, 0, 0);
        a = __builtin_amdgcn_mfma_f32_16x16x32_bf16(ql0, kh0, a, 0, 0, 0);
        a = __builtin_amdgcn_mfma_f32_16x16x32_bf16(ql1, kh1, a, 0, 0, 0);
        acc[i] = a;
    }

    float m4[4];
#pragma unroll
    for (int r = 0; r < 4; ++r) {
        m4[r] = acc[0][r];
#pragma unroll
        for (int i = 1; i < 16; ++i) m4[r] = fmaxf(m4[r], acc[i][r]);
    }
#pragma unroll
    for (int off = 1; off < 16; off <<= 1) {
#pragma unroll
        for (int r = 0; r < 4; ++r) m4[r] = fmaxf(m4[r], __shfl_xor(m4[r], off));
    }
    const int rgrp = l >> 4;
    if ((l & 15) == 0) {
#pragma unroll
        for (int r = 0; r < 4; ++r) wmax[w * 16 + rgrp * 4 + r] = m4[r];
    }
    __syncthreads();
    if (tid < 16) {
        float m = wmax[tid];
#pragma unroll
        for (int ww = 1; ww < 16; ++ww) m = fmaxf(m, wmax[ww * 16 + tid]);
        fmax_s[tid] = m;
    }
    __syncthreads();

    float fm[4];
#pragma unroll
    for (int r = 0; r < 4; ++r) fm[r] = fmax_s[rgrp * 4 + r];
    const int cres = l & 15;
    const size_t obase = ((size_t)b * SLEN + (size_t)rt * 16) * SLEN;
#pragma unroll
    for (int i = 0; i < 16; ++i) {
        const int col = (w * 16 + i) * 16 + cres;
#pragma unroll
        for (int r = 0; r < 4; ++r)
            out[obase + (size_t)(rgrp * 4 + r) * SLEN + col] = __expf(acc[i][r] - fm[r]);
    }
}

extern "C" void kernel_launch(void* const* d_in, const int* in_sizes, int n_in,
                              void* d_out, int out_size, void* d_ws, size_t ws_size,
                              hipStream_t stream) {
    (void)in_sizes; (void)n_in;
    const float* src   = (const float*)d_in[0];
    const float* gamma = (const float*)d_in[1];
    const float* beta  = (const float*)d_in[2];
    const float* Wq    = (const float*)d_in[3];
    const float* bq    = (const float*)d_in[4];
    const float* Wk    = (const float*)d_in[5];
    const float* bk    = (const float*)d_in[6];
    float* out = (float*)d_out;

    // ws: qhf/qlf/khf/klf 1 MB each; then whf/wlf 256 KB each (r5 scheme).
    unsigned short* ws  = (unsigned short*)d_ws;
    unsigned short* qhf = ws;
    unsigned short* qlf = ws + (1u << 19);
    unsigned short* khf = ws + (2u << 19);
    unsigned short* klf = ws + (3u << 19);

    const size_t wfrag_shorts = 131072;             // 256 KB each
    const size_t need_bytes = (4u << 20) + 2 * 256 * 1024;
    unsigned short *whf, *wlf;
    if (ws_size >= need_bytes) {
        whf = ws + (4u << 19);
        wlf = whf + wfrag_shorts;
    } else {
        // park W frags in d_out tail: wprep writes -> ln_proj reads ->
        // score overwrites every byte afterwards (stream-ordered).
        const size_t out_bytes = (size_t)out_size * 4;
        char* tail = (char*)d_out + (out_bytes - (2 * 256 * 1024 + 4096));
        whf = (unsigned short*)tail;
        wlf = whf + wfrag_shorts;
    }

    hipLaunchKernelGGL(wprep_kernel, dim3(64), dim3(256), 0, stream,
                       Wq, Wk, whf, wlf);
    hipLaunchKernelGGL(ln_proj_kernel, dim3(512), dim3(512), 0, stream,
                       src, gamma, beta, bq, bk, whf, wlf, qhf, qlf, khf, klf);
    hipLaunchKernelGGL(score_kernel, dim3(512), dim3(1024), 0, stream,
                       qhf, qlf, khf, klf, out);
}